// Round 1
// baseline (641.909 us; speedup 1.0000x reference)
//
#include <hip/hip_runtime.h>
#include <math.h>

#define ITERS 30

// ws float offsets
#define WS_F    0        // 32768 floats: f[b][n]
#define WS_G    32768    // 4096  floats: g[b][m]
#define WS_LA   36864    // 32768 floats: ln(A+1e-20)
#define WS_P1   69632    // 1024*3 floats: E1 block partials (ent, pix, emdf)
#define WS_P2   72704    // 1024*2 floats: E2 block partials (pnt, emdg)

__device__ __forceinline__ float fexp2(float x){ return __builtin_amdgcn_exp2f(x); }
__device__ __forceinline__ float flog2(float x){ return __builtin_amdgcn_logf(x); }
__device__ __forceinline__ float fsq(float x){ return __builtin_amdgcn_sqrtf(x); }

__device__ __forceinline__ float wave_max(float v){
  #pragma unroll
  for (int off = 1; off < 64; off <<= 1) v = fmaxf(v, __shfl_xor(v, off));
  return v;
}
__device__ __forceinline__ float wave_sum(float v){
  #pragma unroll
  for (int off = 1; off < 64; off <<= 1) v += __shfl_xor(v, off);
  return v;
}

// constants (log2-domain formulation)
// x_g = la + (f - C)/eps ;  C = exp(d/0.6)-1 ; eps=0.01
//   => y = x/ln2 = (la + 100 f + 100)/ln2 - KC * E,  E = 2^(d*K2)
__device__ const float LN2f   = 0.69314718055994530942f;
__device__ const float INVLN2 = 1.44269504088896340736f;
__device__ const float K2     = 2.40449173481494868463f;   // 1/(0.6*ln2)
__device__ const float KC     = 144.269504088896340736f;   // 100/ln2
__device__ const float CNEG   = -0.0067955605937249540f;   // -eps*damping*ln2, damping=0.5/0.51
__device__ const float IRHOL2 = 2.88539008177792681472f;   // 1/(0.5*ln2)  (rho=0.5)

__global__ __launch_bounds__(256) void k_init(const float* __restrict__ A, float* __restrict__ ws){
  int i = blockIdx.x * 256 + threadIdx.x;
  if (i < 32768){
    ws[WS_F + i] = 0.f;
    ws[WS_LA + i] = LN2f * flog2(A[i] + 1e-20f);
  }
  if (i < 4096) ws[WS_G + i] = 0.f;
}

// g[b,m] = CNEG * log2sumexp2_n( P[n] - KC*E(n,m) ),  P = (la + 100 f + 100)/ln2
// one wave per (b,m); lane l owns grid column ix=l; j loops rows iy=0..63.
__global__ __launch_bounds__(256) void k_gupd(const float* __restrict__ pts, float* __restrict__ ws){
  __shared__ float P[4096];
  int blk = blockIdx.x;
  int b = blk >> 7;          // 128 blocks per batch
  int mt = blk & 127;        // 4 m per block
  const float4* f4  = (const float4*)(ws + WS_F  + b*4096);
  const float4* la4 = (const float4*)(ws + WS_LA + b*4096);
  for (int k = threadIdx.x; k < 1024; k += 256){
    float4 fv = f4[k], lv = la4[k];
    float4 o;
    o.x = (lv.x + 100.f*fv.x + 100.f) * INVLN2;
    o.y = (lv.y + 100.f*fv.y + 100.f) * INVLN2;
    o.z = (lv.z + 100.f*fv.z + 100.f) * INVLN2;
    o.w = (lv.w + 100.f*fv.w + 100.f) * INVLN2;
    ((float4*)P)[k] = o;
  }
  __syncthreads();
  int w = threadIdx.x >> 6, l = threadIdx.x & 63;
  int m = mt*4 + w;
  float ymx = pts[(b*512 + m)*2 + 0] * (1.f/512.f);
  float ymy = pts[(b*512 + m)*2 + 1] * (1.f/512.f);
  float xn  = (float)(l + 1) * (1.f/64.f);
  float dx  = xn - ymx;
  float dx2 = __builtin_fmaf(dx, dx, 1e-12f);
  float mrun = -INFINITY, srun = 0.f;
  #pragma unroll
  for (int c = 0; c < 4; ++c){
    float x[16];
    float cm = -INFINITY;
    #pragma unroll
    for (int jj = 0; jj < 16; ++jj){
      int j = c*16 + jj;
      float yn = (float)(j + 1) * (1.f/64.f);
      float dy = yn - ymy;
      float d2 = __builtin_fmaf(dy, dy, dx2);
      float E  = fexp2(fsq(d2) * K2);
      float y  = __builtin_fmaf(-KC, E, P[j*64 + l]);
      x[jj] = y;
      cm = fmaxf(cm, y);
    }
    float mnew = fmaxf(mrun, cm);
    float cs = 0.f;
    #pragma unroll
    for (int jj = 0; jj < 16; ++jj) cs += fexp2(x[jj] - mnew);
    srun = __builtin_fmaf(srun, fexp2(mrun - mnew), cs);
    mrun = mnew;
  }
  float Mx = wave_max(mrun);
  float S  = wave_sum(srun * fexp2(mrun - Mx));
  if (l == 0)
    ws[WS_G + b*512 + m] = CNEG * (Mx + flog2(S));
}

// f[b,n] = CNEG * log2sumexp2_m( G[m] - KC*E(n,m) ),  G = (100 g + 100)/ln2
// one wave per row n; lanes span m (8 per lane).
__global__ __launch_bounds__(256) void k_fupd(const float* __restrict__ pts, float* __restrict__ ws){
  __shared__ float4 Q[512];
  int blk = blockIdx.x;
  int b = blk >> 7;
  int nt = blk & 127;        // 32 rows per block
  const float*  g  = ws + WS_G + b*512;
  const float2* p2 = (const float2*)(pts + b*1024);
  for (int m = threadIdx.x; m < 512; m += 256){
    float2 pv = p2[m];
    Q[m] = make_float4(__builtin_fmaf(g[m], KC, KC), pv.x*(1.f/512.f), pv.y*(1.f/512.f), 0.f);
  }
  __syncthreads();
  int w = threadIdx.x >> 6, l = threadIdx.x & 63;
  #pragma unroll 1
  for (int r = 0; r < 8; ++r){
    int n = nt*32 + w*8 + r;
    float xn = (float)((n & 63) + 1) * (1.f/64.f);
    float yn = (float)((n >> 6) + 1) * (1.f/64.f);
    float x[8]; float cm = -INFINITY;
    #pragma unroll
    for (int jm = 0; jm < 8; ++jm){
      float4 q = Q[jm*64 + l];
      float dxx = q.y - xn, dyy = q.z - yn;
      float d2 = __builtin_fmaf(dyy, dyy, __builtin_fmaf(dxx, dxx, 1e-12f));
      float E  = fexp2(fsq(d2) * K2);
      float y  = __builtin_fmaf(-KC, E, q.x);
      x[jm] = y; cm = fmaxf(cm, y);
    }
    float Mx = wave_max(cm);
    float s = 0.f;
    #pragma unroll
    for (int jm = 0; jm < 8; ++jm) s += fexp2(x[jm] - Mx);
    float S = wave_sum(s);
    if (l == 0)
      ws[WS_F + b*4096 + n] = CNEG * (Mx + flog2(S));
  }
}

// Epilogue pass 1 (row layout): entropy, rowsums -> pixel loss, emd f-part.
// z = (f+g-C)/(eps*ln2) = F2[n] + (G[m] - KC*E);  PI = 2^z * A[n]
__global__ __launch_bounds__(256) void k_ep1(const float* __restrict__ A, const float* __restrict__ pts, float* __restrict__ ws){
  __shared__ float4 Q[512];
  __shared__ float red[12];
  int blk = blockIdx.x;
  int b = blk >> 7;
  int nt = blk & 127;
  const float*  g  = ws + WS_G + b*512;
  const float*  f  = ws + WS_F + b*4096;
  const float*  Ab = A + b*4096;
  const float2* p2 = (const float2*)(pts + b*1024);
  for (int m = threadIdx.x; m < 512; m += 256){
    float2 pv = p2[m];
    Q[m] = make_float4(__builtin_fmaf(g[m], KC, KC), pv.x*(1.f/512.f), pv.y*(1.f/512.f), 0.f);
  }
  __syncthreads();
  int w = threadIdx.x >> 6, l = threadIdx.x & 63;
  float ent = 0.f, pix = 0.f, emdf = 0.f;
  #pragma unroll 1
  for (int r = 0; r < 8; ++r){
    int n = nt*32 + w*8 + r;
    float fn = f[n], An = Ab[n];
    float F2 = fn * KC;
    float xn = (float)((n & 63) + 1) * (1.f/64.f);
    float yn = (float)((n >> 6) + 1) * (1.f/64.f);
    float rs = 0.f;
    #pragma unroll
    for (int jm = 0; jm < 8; ++jm){
      float4 q = Q[jm*64 + l];
      float dxx = q.y - xn, dyy = q.z - yn;
      float d2 = __builtin_fmaf(dyy, dyy, __builtin_fmaf(dxx, dxx, 1e-12f));
      float E  = fexp2(fsq(d2) * K2);
      float z  = F2 + __builtin_fmaf(-KC, E, q.x);
      float p  = fexp2(z) * An;
      rs += p;
      float qq = p + 1e-20f;
      ent = __builtin_fmaf(qq, LN2f * flog2(qq), ent);
    }
    rs = wave_sum(rs);
    if (l == 0){
      pix  += fabsf(rs - An);
      emdf += An * (1.f - fexp2(fn * -IRHOL2));
    }
  }
  ent = wave_sum(ent); pix = wave_sum(pix); emdf = wave_sum(emdf);
  if (l == 0){ red[w*3+0] = ent; red[w*3+1] = pix; red[w*3+2] = emdf; }
  __syncthreads();
  if (threadIdx.x == 0){
    float e = 0.f, p = 0.f, q = 0.f;
    for (int i = 0; i < 4; ++i){ e += red[i*3]; p += red[i*3+1]; q += red[i*3+2]; }
    float* P1 = ws + WS_P1;
    P1[blk*3+0] = e; P1[blk*3+1] = p; P1[blk*3+2] = q;
  }
}

// Epilogue pass 2 (col layout): colsums -> point loss, emd g-part.
// colsum[b,m] = sum_n 2^( W[n] + G2 - KC*E ),  W[n] = 100 f/ln2 + log2(A[n])
__global__ __launch_bounds__(256) void k_ep2(const float* __restrict__ A, const float* __restrict__ pts, float* __restrict__ ws){
  __shared__ float Wn[4096];
  __shared__ float red[8];
  int blk = blockIdx.x;
  int b = blk >> 7;
  int mt = blk & 127;
  const float4* f4 = (const float4*)(ws + WS_F + b*4096);
  const float4* A4 = (const float4*)(A + b*4096);
  for (int k = threadIdx.x; k < 1024; k += 256){
    float4 fv = f4[k], av = A4[k];
    float4 o;
    o.x = __builtin_fmaf(fv.x, KC, flog2(av.x));
    o.y = __builtin_fmaf(fv.y, KC, flog2(av.y));
    o.z = __builtin_fmaf(fv.z, KC, flog2(av.z));
    o.w = __builtin_fmaf(fv.w, KC, flog2(av.w));
    ((float4*)Wn)[k] = o;
  }
  __syncthreads();
  int w = threadIdx.x >> 6, l = threadIdx.x & 63;
  int m = mt*4 + w;
  float gm  = ws[WS_G + b*512 + m];
  float G2  = __builtin_fmaf(gm, KC, KC);
  float ymx = pts[(b*512 + m)*2 + 0] * (1.f/512.f);
  float ymy = pts[(b*512 + m)*2 + 1] * (1.f/512.f);
  float xn  = (float)(l + 1) * (1.f/64.f);
  float dx  = xn - ymx;
  float dx2 = __builtin_fmaf(dx, dx, 1e-12f);
  float cs = 0.f;
  #pragma unroll
  for (int j = 0; j < 64; ++j){
    float yn = (float)(j + 1) * (1.f/64.f);
    float dy = yn - ymy;
    float d2 = __builtin_fmaf(dy, dy, dx2);
    float E  = fexp2(fsq(d2) * K2);
    float z  = G2 + __builtin_fmaf(-KC, E, Wn[j*64 + l]);
    cs += fexp2(z);
  }
  cs = wave_sum(cs);
  if (l == 0){
    red[w*2+0] = fabsf(cs - 1.f);
    red[w*2+1] = 1.f - fexp2(gm * -IRHOL2);
  }
  __syncthreads();
  if (threadIdx.x == 0){
    float p = 0.f, e = 0.f;
    for (int i = 0; i < 4; ++i){ p += red[i*2]; e += red[i*2+1]; }
    float* P2 = ws + WS_P2;
    P2[blk*2+0] = p; P2[blk*2+1] = e;
  }
}

__global__ __launch_bounds__(256) void k_fin(const float* __restrict__ ws, float* __restrict__ out){
  __shared__ float red[20];
  float e = 0.f, pix = 0.f, emdf = 0.f, pnt = 0.f, emdg = 0.f;
  for (int i = threadIdx.x; i < 1024; i += 256){
    e    += ws[WS_P1 + i*3 + 0];
    pix  += ws[WS_P1 + i*3 + 1];
    emdf += ws[WS_P1 + i*3 + 2];
    pnt  += ws[WS_P2 + i*2 + 0];
    emdg += ws[WS_P2 + i*2 + 1];
  }
  e = wave_sum(e); pix = wave_sum(pix); emdf = wave_sum(emdf);
  pnt = wave_sum(pnt); emdg = wave_sum(emdg);
  int w = threadIdx.x >> 6, l = threadIdx.x & 63;
  if (l == 0){
    red[w*5+0] = e; red[w*5+1] = pix; red[w*5+2] = emdf; red[w*5+3] = pnt; red[w*5+4] = emdg;
  }
  __syncthreads();
  if (threadIdx.x == 0){
    float E = 0.f, PX = 0.f, EF = 0.f, PT = 0.f, EG = 0.f;
    for (int i = 0; i < 4; ++i){
      E += red[i*5]; PX += red[i*5+1]; EF += red[i*5+2]; PT += red[i*5+3]; EG += red[i*5+4];
    }
    float emd = 0.5f * (EF + EG);                   // RHO * sums
    float entropy = E * (1.f / (4096.f * 512.f));   // mean over (n,m), summed over b
    out[0] = emd + 0.1f * (PX + PT) + 0.01f * entropy;
  }
}

extern "C" void kernel_launch(void* const* d_in, const int* in_sizes, int n_in,
                              void* d_out, int out_size, void* d_ws, size_t ws_size,
                              hipStream_t stream) {
  const float* A   = (const float*)d_in[0];   // predict_map [8,1,64,64]
  const float* pts = (const float*)d_in[1];   // points [8,512,2]
  float* ws  = (float*)d_ws;
  float* out = (float*)d_out;

  k_init<<<128, 256, 0, stream>>>(A, ws);
  for (int it = 0; it < ITERS; ++it){
    k_gupd<<<1024, 256, 0, stream>>>(pts, ws);
    k_fupd<<<1024, 256, 0, stream>>>(pts, ws);
  }
  k_ep1<<<1024, 256, 0, stream>>>(A, pts, ws);
  k_ep2<<<1024, 256, 0, stream>>>(A, pts, ws);
  k_fin<<<1, 256, 0, stream>>>(ws, out);
}